// Round 4
// baseline (483.383 us; speedup 1.0000x reference)
//
#include <hip/hip_runtime.h>
#include <hip/hip_bf16.h>
#include <math.h>

// Problem constants
#define N_ROWS 16384
#define N_A    256
#define N_F    2048
#define GAMMA  1.5f
#define BN_EPS 1e-5f

typedef __attribute__((ext_vector_type(8))) short short8;
typedef __attribute__((ext_vector_type(4))) float f32x4;

// ---------------------------------------------------------------------------
// K0: fp32 -> bf16 conversion (4 elements/thread, vectorized) — validated
// ---------------------------------------------------------------------------
__global__ __launch_bounds__(256) void cvt_bf16(const float* __restrict__ in,
                                                unsigned short* __restrict__ out,
                                                int n4) {
    int i = blockIdx.x * 256 + threadIdx.x;
    if (i >= n4) return;
    float4 v = reinterpret_cast<const float4*>(in)[i];
    ushort4 o;
    o.x = __builtin_bit_cast(unsigned short, __float2bfloat16(v.x));
    o.y = __builtin_bit_cast(unsigned short, __float2bfloat16(v.y));
    o.z = __builtin_bit_cast(unsigned short, __float2bfloat16(v.z));
    o.w = __builtin_bit_cast(unsigned short, __float2bfloat16(v.w));
    reinterpret_cast<ushort4*>(out)[i] = o;
}

// ---------------------------------------------------------------------------
// K1: x = a @ W^T + b. R3 kernel upgraded to the m97 two-phase structure:
// BK=64 slabs (4 of them), BOTH A and W staged via global_load_lds width=16
// with XOR-pre-swizzled GLOBAL source (LDS dest linear — m104/m173 rule;
// involution verified: (koff^swz)+j then ^swz = koff+j since koff is 16B-
// aligned and swz only touches bits 4-6). Double-buffered: stage slab s+1
// overlaps MFMA on slab s; __syncthreads() (which drains vmcnt) separates.
// K-step order (global k 0..255 in 8 steps of 32), MFMA sequence, bias add,
// stats reduction, and LDS-transpose x store are bit-identical to the
// validated R3 kernel. XCD-aware bijective block swizzle (2048%8==0): each
// XCD owns 16 contiguous row-panels -> A fetched ~once per XCD.
// LDS: As[2][128][64]bf16 (32K) + Ws[2][128][64] (32K); epilogue reuses the
// first 34.8KB as the transpose tile. 66KB total -> 2 blocks/CU.
// ---------------------------------------------------------------------------
__global__ __launch_bounds__(256) void gemm_x(const unsigned short* __restrict__ aB,
                                              const unsigned short* __restrict__ wB,
                                              const float* __restrict__ bias,
                                              unsigned short* __restrict__ xB,
                                              float* __restrict__ ps1,
                                              float* __restrict__ ps2) {
    const int tid  = threadIdx.x;
    const int lane = tid & 63;
    const int wave = tid >> 6;
    const int r16  = lane & 15;
    const int quad = lane >> 4;

    // bijective XCD swizzle: id -> (id%8)*256 + id/8
    const int id   = blockIdx.y * 16 + blockIdx.x;
    const int nid  = (id & 7) * 256 + (id >> 3);
    const int bx   = nid & 15;
    const int by   = nid >> 4;
    const int col0 = bx * 128;
    const int rowB = by * 128;

    __shared__ char smem[65536];        // [As 2x16K][Ws 2x16K]; reused as tile
    char* As = smem;
    char* Ws = smem + 32768;

    // stage one BK=64 slab of A and W into buffer bo (0 or 16384).
    // chunk c = i*256+tid: row = c>>3 (8x16B per 128B row), lane-linear dest.
    auto STAGE = [&](int bo, int slab) {
        const char* asrc = (const char*)(aB + (size_t)rowB * N_A + slab * 64);
        const char* wsrc = (const char*)(wB + (size_t)col0 * N_A + slab * 64);
        #pragma unroll
        for (int i = 0; i < 4; ++i) {
            const int c   = i * 256 + tid;
            const int row = c >> 3;
            const int off = (c & 7) * 16;
            const int src = off ^ ((row & 7) << 4);
            __builtin_amdgcn_global_load_lds(
                (const __attribute__((address_space(1))) void*)(asrc + (size_t)row * 512 + src),
                (__attribute__((address_space(3))) void*)(As + bo + c * 16), 16, 0, 0);
            __builtin_amdgcn_global_load_lds(
                (const __attribute__((address_space(1))) void*)(wsrc + (size_t)row * 512 + src),
                (__attribute__((address_space(3))) void*)(Ws + bo + c * 16), 16, 0, 0);
        }
    };

    f32x4 acc[2][8];
    #pragma unroll
    for (int g = 0; g < 2; ++g)
        #pragma unroll
        for (int t = 0; t < 8; ++t)
            acc[g][t] = (f32x4){0.f, 0.f, 0.f, 0.f};

    STAGE(0, 0);
    __syncthreads();                    // vmcnt(0) drain + barrier: slab0 ready

    const int swz = (r16 & 7) << 4;     // row&7 == r16&7 for all fragment rows
    #pragma unroll
    for (int s = 0; s < 4; ++s) {
        const int bo = (s & 1) * 16384;
        if (s < 3) STAGE(bo ^ 16384, s + 1);   // overlap next stage with MFMA
        #pragma unroll
        for (int ks = 0; ks < 2; ++ks) {
            const int koff = (ks * 64 + quad * 16) ^ swz;   // swizzled byte-in-row
            short8 a0 = *reinterpret_cast<const short8*>(
                            As + bo + (wave * 32 + r16) * 128 + koff);
            short8 a1 = *reinterpret_cast<const short8*>(
                            As + bo + (wave * 32 + 16 + r16) * 128 + koff);
            #pragma unroll
            for (int t = 0; t < 8; ++t) {
                short8 bf = *reinterpret_cast<const short8*>(
                                Ws + bo + (t * 16 + r16) * 128 + koff);
                acc[0][t] = __builtin_amdgcn_mfma_f32_16x16x32_bf16(a0, bf, acc[0][t], 0, 0, 0);
                acc[1][t] = __builtin_amdgcn_mfma_f32_16x16x32_bf16(a1, bf, acc[1][t], 0, 0, 0);
            }
        }
        __syncthreads();                // drains next-slab vmcnt; guards buf reuse
    }

    __shared__ float cs1[4][128];
    __shared__ float cs2[4][128];
    unsigned short (*tile)[136] = (unsigned short (*)[136])smem;  // 34.8 KB reuse

    #pragma unroll
    for (int t = 0; t < 8; ++t) {
        const float bcol = bias[col0 + t * 16 + r16];
        float s1 = 0.f, s2 = 0.f;
        #pragma unroll
        for (int g = 0; g < 2; ++g) {
            #pragma unroll
            for (int r = 0; r < 4; ++r) {
                float v = acc[g][t][r] + bcol;
                s1 += v;
                s2 += v * v;
                tile[wave * 32 + g * 16 + quad * 4 + r][t * 16 + r16] =
                    __builtin_bit_cast(unsigned short, __float2bfloat16(v));
            }
        }
        // reduce across the 4 quads (rows) -> per-column sums over 32 rows
        s1 += __shfl_xor(s1, 16); s1 += __shfl_xor(s1, 32);
        s2 += __shfl_xor(s2, 16); s2 += __shfl_xor(s2, 32);
        if (quad == 0) { cs1[wave][t * 16 + r16] = s1; cs2[wave][t * 16 + r16] = s2; }
    }
    __syncthreads();

    if (threadIdx.x < 128) {
        const int c = threadIdx.x;
        float s1 = cs1[0][c] + cs1[1][c] + cs1[2][c] + cs1[3][c];
        float s2 = cs2[0][c] + cs2[1][c] + cs2[2][c] + cs2[3][c];
        ps1[(size_t)by * N_F + col0 + c] = s1;
        ps2[(size_t)by * N_F + col0 + c] = s2;
    }

    // coalesced bf16 tile store: 256 threads x 128 B each
    {
        const int r = threadIdx.x >> 1;
        const int h = threadIdx.x & 1;
        const unsigned short* src = &tile[r][h * 64];
        unsigned short* dst = xB + (size_t)(rowB + r) * 4096 + col0 + h * 64;
        #pragma unroll
        for (int i = 0; i < 8; ++i)
            *reinterpret_cast<short8*>(dst + i * 8) =
                *reinterpret_cast<const short8*>(src + i * 8);
    }
}

// ---------------------------------------------------------------------------
// K2: finalize BN stats (sum 128 deterministic partials) -> scale/shift
// — VERBATIM validated.
// ---------------------------------------------------------------------------
__global__ __launch_bounds__(256) void finalize_stats(const float* __restrict__ ps1,
                                                      const float* __restrict__ ps2,
                                                      const float* __restrict__ bn_w,
                                                      const float* __restrict__ bn_b,
                                                      float* __restrict__ scale,
                                                      float* __restrict__ shift) {
    const int f = blockIdx.x * 256 + threadIdx.x;
    float s1 = 0.f, s2 = 0.f;
    #pragma unroll 4
    for (int i = 0; i < 128; ++i) {
        s1 += ps1[(size_t)i * N_F + f];
        s2 += ps2[(size_t)i * N_F + f];
    }
    const float inv_n = 1.0f / (float)N_ROWS;
    const float mu  = s1 * inv_n;
    const float var = s2 * inv_n - mu * mu;
    const float sc  = bn_w[f] / sqrtf(var + BN_EPS);
    scale[f] = sc;
    shift[f] = bn_b[f] - mu * sc;
}

// ---------------------------------------------------------------------------
// K3: fused BN + sparsemax + prior update, wave-per-row. 4 rows/block (one
// wave each), lane handles 32 features in 4 contiguous 512-col chunks.
// Row reduction = pure 64-lane shfl butterfly: no LDS, no barriers. The
// xB-read -> aliased m_out-write ordering is enforced by the shfl data
// dependence (writes depend on the full reduction). Same tau shortcut as the
// validated kernel; only fp32 summation order differs (~1e-6 on tau).
// ps is re-read at store time (L2-hot), matching the validated pattern.
// ---------------------------------------------------------------------------
__global__ __launch_bounds__(256) void bn_sparsemax(const unsigned short* xB,
                                                    const float* __restrict__ ps,
                                                    const float* __restrict__ scale,
                                                    const float* __restrict__ shift,
                                                    float* m_out,
                                                    float* __restrict__ ps_out) {
    const int wave = threadIdx.x >> 6;
    const int lane = threadIdx.x & 63;
    const int row  = blockIdx.x * 4 + wave;

    const unsigned short* xr = xB + (size_t)row * 4096;
    const float* pr = ps + (size_t)row * N_F;

    float z[32];
    float s = 0.f, mx = -INFINITY, mn = INFINITY;
    #pragma unroll
    for (int c = 0; c < 4; ++c) {
        const int f0 = c * 512 + lane * 8;
        short8 xv  = *reinterpret_cast<const short8*>(xr + f0);
        float4 p0  = *reinterpret_cast<const float4*>(pr + f0);
        float4 p1  = *reinterpret_cast<const float4*>(pr + f0 + 4);
        float4 sc0 = *reinterpret_cast<const float4*>(scale + f0);
        float4 sc1 = *reinterpret_cast<const float4*>(scale + f0 + 4);
        float4 sh0 = *reinterpret_cast<const float4*>(shift + f0);
        float4 sh1 = *reinterpret_cast<const float4*>(shift + f0 + 4);
        float pvc[8] = {p0.x, p0.y, p0.z, p0.w, p1.x, p1.y, p1.z, p1.w};
        float scv[8] = {sc0.x, sc0.y, sc0.z, sc0.w, sc1.x, sc1.y, sc1.z, sc1.w};
        float shv[8] = {sh0.x, sh0.y, sh0.z, sh0.w, sh1.x, sh1.y, sh1.z, sh1.w};
        #pragma unroll
        for (int i = 0; i < 8; ++i) {
            float xf = __builtin_bit_cast(float,
                           (unsigned int)((unsigned short)xv[i]) << 16);
            float zz = (xf * scv[i] + shv[i]) * pvc[i];
            z[c * 8 + i] = zz;
            s += zz;
            mx = fmaxf(mx, zz);
            mn = fminf(mn, zz);
        }
    }

    // 64-lane butterfly reduction (all lanes end with the row totals)
    #pragma unroll
    for (int off = 32; off > 0; off >>= 1) {
        s  += __shfl_xor(s, off);
        mx  = fmaxf(mx, __shfl_xor(mx, off));
        mn  = fminf(mn, __shfl_xor(mn, off));
    }

    const float c_last = 1.0f + (float)(N_F - 1) * mx - s;
    const float tau = (c_last > 0.0f) ? (s + 1.0f) / (float)(N_F - 1)
                                      : (mn + 1.0f) / 0.0f;   // degenerate k_z=0

    float* mo = m_out  + (size_t)row * N_F;
    float* po = ps_out + (size_t)row * N_F;
    #pragma unroll
    for (int c = 0; c < 4; ++c) {
        const int f0 = c * 512 + lane * 8;
        float4 p0 = *reinterpret_cast<const float4*>(pr + f0);
        float4 p1 = *reinterpret_cast<const float4*>(pr + f0 + 4);
        float4 mv0, mv1, po0, po1;
        mv0.x = fmaxf(z[c*8+0] - tau, 0.f); po0.x = p0.x * (GAMMA - mv0.x);
        mv0.y = fmaxf(z[c*8+1] - tau, 0.f); po0.y = p0.y * (GAMMA - mv0.y);
        mv0.z = fmaxf(z[c*8+2] - tau, 0.f); po0.z = p0.z * (GAMMA - mv0.z);
        mv0.w = fmaxf(z[c*8+3] - tau, 0.f); po0.w = p0.w * (GAMMA - mv0.w);
        mv1.x = fmaxf(z[c*8+4] - tau, 0.f); po1.x = p1.x * (GAMMA - mv1.x);
        mv1.y = fmaxf(z[c*8+5] - tau, 0.f); po1.y = p1.y * (GAMMA - mv1.y);
        mv1.z = fmaxf(z[c*8+6] - tau, 0.f); po1.z = p1.z * (GAMMA - mv1.z);
        mv1.w = fmaxf(z[c*8+7] - tau, 0.f); po1.w = p1.w * (GAMMA - mv1.w);
        *reinterpret_cast<float4*>(mo + f0)     = mv0;
        *reinterpret_cast<float4*>(mo + f0 + 4) = mv1;
        *reinterpret_cast<float4*>(po + f0)     = po0;
        *reinterpret_cast<float4*>(po + f0 + 4) = po1;
    }
}

// ---------------------------------------------------------------------------
extern "C" void kernel_launch(void* const* d_in, const int* in_sizes, int n_in,
                              void* d_out, int out_size, void* d_ws, size_t ws_size,
                              hipStream_t stream) {
    const float* a    = (const float*)d_in[0];  // [N, 256]
    const float* ps   = (const float*)d_in[1];  // [N, 2048]
    const float* W    = (const float*)d_in[2];  // [2048, 256]
    const float* bias = (const float*)d_in[3];  // [2048]
    const float* bnw  = (const float*)d_in[4];
    const float* bnb  = (const float*)d_in[5];

    float* out    = (float*)d_out;
    float* m_out  = out;
    float* ps_out = out + (size_t)N_ROWS * N_F;
    // bf16 x lives interleaved in the m region: row r occupies the first
    // 4096 B of m-row r (stride 4096 ushorts = 8192 B).
    unsigned short* xB = (unsigned short*)d_out;

    char* ws = (char*)d_ws;
    unsigned short* aB = (unsigned short*)ws;                    // 8 MB
    unsigned short* wB = (unsigned short*)(ws + (8u << 20));     // 1 MB
    float* ps1   = (float*)(ws + (9u  << 20));                   // 1 MB (128x2048)
    float* ps2   = (float*)(ws + (10u << 20));                   // 1 MB
    float* scale = (float*)(ws + (11u << 20));                   // 8 KB
    float* shift = (float*)(ws + (11u << 20) + 8192);            // 8 KB

    cvt_bf16<<<4096, 256, 0, stream>>>(a, aB, N_ROWS * N_A / 4);
    cvt_bf16<<<512, 256, 0, stream>>>(W, wB, N_F * N_A / 4);
    gemm_x<<<dim3(N_F / 128, N_ROWS / 128), 256, 0, stream>>>(aB, wB, bias, xB, ps1, ps2);
    finalize_stats<<<N_F / 256, 256, 0, stream>>>(ps1, ps2, bnw, bnb, scale, shift);
    bn_sparsemax<<<N_ROWS / 4, 256, 0, stream>>>(xB, ps, scale, shift, m_out, ps_out);
}